// Round 1
// baseline (573.296 us; speedup 1.0000x reference)
//
#include <hip/hip_runtime.h>

typedef unsigned short u16;
typedef unsigned int u32;
typedef __attribute__((ext_vector_type(8))) short short8;
typedef __attribute__((ext_vector_type(4))) float f32x4;

#define BB 512
#define TT 128
#define DD 128
#define HH 4
#define NBB 2
#define BT (BB*TT)
#define EPSF 1e-5f

__device__ __forceinline__ float bf2f(u16 u){ return __uint_as_float(((u32)u) << 16); }
__device__ __forceinline__ u16 f2bf(float f){
  u32 x = __float_as_uint(f);
  u32 r = x + 0x7fffu + ((x >> 16) & 1u);
  return (u16)(r >> 16);
}
__device__ __forceinline__ float bcastf(float v, int lane){
  return __uint_as_float(__builtin_amdgcn_readlane(__float_as_uint(v), lane));
}
__device__ __forceinline__ float fast_tanh(float x){
  float ax = fabsf(x);
  float e = __expf(-2.f * ax);
  float t = (1.f - e) / (1.f + e);
  return copysignf(t, x);
}
__device__ __forceinline__ float gelu_tanh(float x){
  float u = 0.7978845608028654f * (x + 0.044715f * x * x * x);
  return 0.5f * x * (1.f + fast_tanh(u));
}
__device__ __forceinline__ float wredsum64(float v){
  #pragma unroll
  for (int m = 32; m; m >>= 1) v += __shfl_xor(v, m, 64);
  return v;
}

// ---------------- weight conversion to bf16 (transposed for MFMA B-frags) ----
// w1T: [NB][384 n][128 k]   from ff_w1 [NB][128 k][384 n]
// w2T: [NB][128 n][192 k]   from ff_w2 [NB][192 k][128 n]
// gifT:[NB][H][64 n][32 k]  n<32 -> Wi[h][k][n], else Wf[h][k][n-32]
// gzoT: same with Wz/Wo
__global__ __launch_bounds__(256) void k_convert(
    const float* __restrict__ ff_w1, const float* __restrict__ ff_w2,
    const float* __restrict__ Wi, const float* __restrict__ Wf,
    const float* __restrict__ Wz, const float* __restrict__ Wo,
    u16* __restrict__ w1T, u16* __restrict__ w2T,
    u16* __restrict__ gifT, u16* __restrict__ gzoT){
  int tid = blockIdx.x * 256 + threadIdx.x;
  const int n1 = NBB*384*128;
  if (tid < n1){
    int nb = tid / (384*128); int r = tid - nb*384*128; int n = r >> 7, k = r & 127;
    w1T[tid] = f2bf(ff_w1[(nb*128 + k)*384 + n]); return;
  }
  tid -= n1;
  const int n2 = NBB*128*192;
  if (tid < n2){
    int nb = tid / (128*192); int r = tid - nb*128*192; int n = r / 192, k = r - n*192;
    w2T[tid] = f2bf(ff_w2[(nb*192 + k)*128 + n]); return;
  }
  tid -= n2;
  const int n3 = NBB*HH*64*32;
  if (tid < n3){
    int nb = tid / (HH*64*32); int r = tid - nb*HH*64*32;
    int h = r >> 11; int r2 = r & 2047; int n = r2 >> 5, k = r2 & 31;
    const float* W = (n < 32) ? Wi : Wf; int nn = n & 31;
    gifT[tid] = f2bf(W[((nb*HH + h)*32 + k)*32 + nn]); return;
  }
  tid -= n3;
  if (tid < n3){
    int nb = tid / (HH*64*32); int r = tid - nb*HH*64*32;
    int h = r >> 11; int r2 = r & 2047; int n = r2 >> 5, k = r2 & 31;
    const float* W = (n < 32) ? Wz : Wo; int nn = n & 31;
    gzoT[tid] = f2bf(W[((nb*HH + h)*32 + k)*32 + nn]); return;
  }
}

// ---------------- embedding gather ----------------
__global__ __launch_bounds__(256) void k_embed(const int* __restrict__ tok,
                                               const float* __restrict__ emb,
                                               float* __restrict__ x){
  int tid = blockIdx.x * 256 + threadIdx.x;   // one float4 each
  int row = tid >> 5, c = tid & 31;
  if (row < BT){
    ((f32x4*)x)[(size_t)row*32 + c] = ((const f32x4*)emb)[(size_t)tok[row]*32 + c];
  }
}

// ---------------- LN1 + causal depthwise conv + silu ----------------
// block = (b, 32-token tile); writes xn_bf (LN1 out) and xc_bf (silu(conv))
__global__ __launch_bounds__(256) void k_lnconv(const float* __restrict__ x,
    const float* __restrict__ ln1_w, const float* __restrict__ conv_w,
    const float* __restrict__ conv_b, u16* __restrict__ xn_bf,
    u16* __restrict__ xc_bf, int nb){
  __shared__ float lnbuf[35][128];
  int b = blockIdx.x >> 2, tile = blockIdx.x & 3;
  int t0 = tile * 32;
  int wid = threadIdx.x >> 6, l = threadIdx.x & 63;
  for (int tt = wid; tt < 35; tt += 4){
    int t = t0 - 3 + tt;
    if (t < 0){
      lnbuf[tt][2*l] = 0.f; lnbuf[tt][2*l+1] = 0.f;
    } else {
      float2 v = ((const float2*)(x + (size_t)(b*TT + t)*128))[l];
      float s  = wredsum64(v.x + v.y);
      float sq = wredsum64(v.x*v.x + v.y*v.y);
      float mu = s * (1.f/128.f);
      float var = sq * (1.f/128.f) - mu*mu;
      float rs = rsqrtf(var + EPSF);
      float2 w = ((const float2*)(ln1_w + nb*128))[l];
      float y0 = (v.x - mu)*rs*w.x, y1 = (v.y - mu)*rs*w.y;
      lnbuf[tt][2*l] = y0; lnbuf[tt][2*l+1] = y1;
      if (tt >= 3){
        u32 pk = (u32)f2bf(y0) | ((u32)f2bf(y1) << 16);
        ((u32*)(xn_bf + (size_t)(b*TT + t)*128))[l] = pk;
      }
    }
  }
  __syncthreads();
  for (int e = threadIdx.x; e < 32*128; e += 256){
    int tt = e >> 7, d = e & 127;
    float s = conv_b[nb*128 + d];
    #pragma unroll
    for (int k = 0; k < 4; k++)
      s += lnbuf[tt + k][d] * conv_w[(nb*128 + d)*4 + k];
    float sig = 1.f / (1.f + __expf(-s));
    xc_bf[(size_t)(b*TT + t0 + tt)*128 + d] = f2bf(s * sig);
  }
}

// ---------------- gate projections (MFMA) ----------------
// grid (M/64, H, 2); z=0: [i|f] from xc; z=1: [z|o] from xn
// gates layout: [row][h*128 + z*64 + col]
__global__ __launch_bounds__(256) void k_gates(const u16* __restrict__ xc_bf,
    const u16* __restrict__ xn_bf, const u16* __restrict__ gifT,
    const u16* __restrict__ gzoT, u16* __restrict__ gates, int nb){
  int m0 = blockIdx.x * 64;
  int h = blockIdx.y, z = blockIdx.z;
  int wid = threadIdx.x >> 6, l = threadIdx.x & 63;
  const u16* A  = z ? xn_bf : xc_bf;
  const u16* Bw = (z ? gzoT : gifT) + (size_t)(nb*HH + h)*64*32;
  int r0 = m0 + wid*16;
  short8 a = *(const short8*)(A + (size_t)(r0 + (l & 15))*128 + h*32 + (l >> 4)*8);
  #pragma unroll
  for (int jt = 0; jt < 4; jt++){
    f32x4 acc = {0.f, 0.f, 0.f, 0.f};
    short8 bf = *(const short8*)(Bw + (jt*16 + (l & 15))*32 + (l >> 4)*8);
    acc = __builtin_amdgcn_mfma_f32_16x16x32_bf16(a, bf, acc, 0, 0, 0);
    int col = z*64 + jt*16 + (l & 15);
    #pragma unroll
    for (int r = 0; r < 4; r++){
      int row = r0 + (l >> 4)*4 + r;
      gates[(size_t)row*512 + h*128 + col] = f2bf(acc[r]);
    }
  }
}

// ---------------- sLSTM recurrent scan + group-norm + residual ----------------
// one wave per (batch, head); lane l owns gate columns l and l+64
__global__ __launch_bounds__(256) void k_scan(const u16* __restrict__ gates,
    const float* __restrict__ Rk, const float* __restrict__ cell_b,
    const float* __restrict__ gn_w, float* __restrict__ x, int nb){
  int wid = threadIdx.x >> 6, l = threadIdx.x & 63;
  int pair = blockIdx.x * 4 + wid;       // 2048
  int b = pair >> 2, h = pair & 3;
  float rk0[32], rk1[32];
  const float* Rkh = Rk + (size_t)(nb*HH + h)*32*128;
  #pragma unroll
  for (int d = 0; d < 32; d++){
    rk0[d] = Rkh[d*128 + l];
    rk1[d] = Rkh[d*128 + l + 64];
  }
  float cb0 = cell_b[(nb*HH + h)*128 + l];
  float cb1 = cell_b[(nb*HH + h)*128 + l + 64];
  int e = l & 31;
  float gnw = gn_w[nb*128 + h*32 + e];
  float hs = 0.f, cs = 0.f, ns = 0.f, ms = 0.f;
  const u16* gp = gates + (size_t)(b*TT)*512 + h*128;
  float* xp = x + (size_t)(b*TT)*128 + h*32;
  u16 pg0 = gp[l], pg1 = gp[l + 64];
  for (int t = 0; t < 128; t++){
    float g0 = bf2f(pg0), g1 = bf2f(pg1);
    // prefetch next step (overreads 1KB past gates at the very end; ws mapped)
    pg0 = gp[512 + l]; pg1 = gp[512 + l + 64];
    float r0a = g0 + cb0, r1a = g1 + cb1, r0b = 0.f, r1b = 0.f;
    #pragma unroll
    for (int d = 0; d < 32; d += 2){
      float hd0 = bcastf(hs, d);
      float hd1 = bcastf(hs, d + 1);
      r0a = fmaf(hd0, rk0[d],   r0a);
      r1a = fmaf(hd0, rk1[d],   r1a);
      r0b = fmaf(hd1, rk0[d+1], r0b);
      r1b = fmaf(hd1, rk1[d+1], r1b);
    }
    float r0 = r0a + r0b, r1 = r1a + r1b;
    float fx = __shfl_xor(r0, 32, 64);   // lane e<32 gets fr[e]
    float ox = __shfl_xor(r1, 32, 64);   // lane e<32 gets og[e]
    // lanes <32: ir=r0, zr=r1
    float mnew = fmaxf(fx + ms, r0);
    float ig = __expf(r0 - mnew);
    float fg = __expf(fx + ms - mnew);
    cs = fg*cs + ig*fast_tanh(r1);
    ns = fg*ns + ig;
    ms = mnew;
    hs = (cs / ns) * (1.f / (1.f + __expf(-ox)));
    // group norm over the 32 head dims (lanes 0..31 hold them)
    float s = hs, sq = hs*hs;
    #pragma unroll
    for (int m = 16; m; m >>= 1){
      s  += __shfl_xor(s,  m, 64);
      sq += __shfl_xor(sq, m, 64);
    }
    float mu = s * (1.f/32.f);
    float var = sq * (1.f/32.f) - mu*mu;
    float yn = (hs - mu) * rsqrtf(var + EPSF) * gnw;
    if (l < 32) xp[e] += yn;
    gp += 512; xp += 128;
  }
}

// ---------------- LN2 + FFN up-proj + gelu*up (MFMA) ----------------
__global__ __launch_bounds__(256) void k_ff1(const float* __restrict__ x,
    const float* __restrict__ ln2_w, const u16* __restrict__ w1T,
    const float* __restrict__ ff_b1, u16* __restrict__ act, int nb){
  __shared__ u16 lnb[64][128];
  int m0 = blockIdx.x * 64;
  int wid = threadIdx.x >> 6, l = threadIdx.x & 63;
  float2 w = ((const float2*)(ln2_w + nb*128))[l];
  for (int rr = 0; rr < 16; rr++){
    int row = wid*16 + rr;
    float2 v = ((const float2*)(x + (size_t)(m0 + row)*128))[l];
    float s  = wredsum64(v.x + v.y);
    float sq = wredsum64(v.x*v.x + v.y*v.y);
    float mu = s * (1.f/128.f);
    float var = sq * (1.f/128.f) - mu*mu;
    float rs = rsqrtf(var + EPSF);
    float y0 = (v.x - mu)*rs*w.x, y1 = (v.y - mu)*rs*w.y;
    ((u32*)lnb[row])[l] = (u32)f2bf(y0) | ((u32)f2bf(y1) << 16);
  }
  __syncthreads();
  short8 a[4];
  #pragma unroll
  for (int c = 0; c < 4; c++)
    a[c] = *(const short8*)(&lnb[wid*16 + (l & 15)][c*32 + (l >> 4)*8]);
  const u16* W = w1T + (size_t)nb*384*128;
  f32x4 acc[24];
  #pragma unroll
  for (int jt = 0; jt < 24; jt++){
    acc[jt] = {0.f, 0.f, 0.f, 0.f};
    #pragma unroll
    for (int c = 0; c < 4; c++){
      short8 bf = *(const short8*)(W + (size_t)(jt*16 + (l & 15))*128 + c*32 + (l >> 4)*8);
      acc[jt] = __builtin_amdgcn_mfma_f32_16x16x32_bf16(a[c], bf, acc[jt], 0, 0, 0);
    }
  }
  #pragma unroll
  for (int jt = 0; jt < 12; jt++){
    int colg = jt*16 + (l & 15);
    float bg = ff_b1[nb*384 + colg];
    float bu = ff_b1[nb*384 + 192 + colg];
    #pragma unroll
    for (int r = 0; r < 4; r++){
      int row = m0 + wid*16 + (l >> 4)*4 + r;
      float gh = acc[jt][r] + bg;
      float uh = acc[jt + 12][r] + bu;
      act[(size_t)row*192 + colg] = f2bf(gelu_tanh(gh) * uh);
    }
  }
}

// ---------------- FFN down-proj + residual (MFMA) ----------------
__global__ __launch_bounds__(256) void k_ff2(const u16* __restrict__ act,
    const u16* __restrict__ w2T, const float* __restrict__ ff_b2,
    float* __restrict__ x, int nb){
  int m0 = blockIdx.x * 64;
  int wid = threadIdx.x >> 6, l = threadIdx.x & 63;
  short8 a[6];
  #pragma unroll
  for (int c = 0; c < 6; c++)
    a[c] = *(const short8*)(act + (size_t)(m0 + wid*16 + (l & 15))*192 + c*32 + (l >> 4)*8);
  const u16* W = w2T + (size_t)nb*128*192;
  #pragma unroll
  for (int jt = 0; jt < 8; jt++){
    f32x4 acc = {0.f, 0.f, 0.f, 0.f};
    #pragma unroll
    for (int c = 0; c < 6; c++){
      short8 bf = *(const short8*)(W + (size_t)(jt*16 + (l & 15))*192 + c*32 + (l >> 4)*8);
      acc = __builtin_amdgcn_mfma_f32_16x16x32_bf16(a[c], bf, acc, 0, 0, 0);
    }
    int col = jt*16 + (l & 15);
    float bias = ff_b2[nb*128 + col];
    #pragma unroll
    for (int r = 0; r < 4; r++){
      int row = m0 + wid*16 + (l >> 4)*4 + r;
      x[(size_t)row*128 + col] += acc[r] + bias;
    }
  }
}

// ---------------- post-LN + mean-pool + classifier ----------------
__global__ __launch_bounds__(256) void k_pool_cls(const float* __restrict__ x,
    const float* __restrict__ pw, const float* __restrict__ w1,
    const float* __restrict__ b1, const float* __restrict__ w2,
    const float* __restrict__ b2, float* __restrict__ out){
  __shared__ float red[4][128];
  __shared__ float pooled[128];
  __shared__ float h1s[64];
  int b = blockIdx.x;
  int wid = threadIdx.x >> 6, l = threadIdx.x & 63;
  float2 w = ((const float2*)pw)[l];
  float ax = 0.f, ay = 0.f;
  for (int t = wid; t < TT; t += 4){
    float2 v = ((const float2*)(x + (size_t)(b*TT + t)*128))[l];
    float s  = wredsum64(v.x + v.y);
    float sq = wredsum64(v.x*v.x + v.y*v.y);
    float mu = s * (1.f/128.f);
    float var = sq * (1.f/128.f) - mu*mu;
    float rs = rsqrtf(var + EPSF);
    ax += (v.x - mu)*rs*w.x;
    ay += (v.y - mu)*rs*w.y;
  }
  red[wid][2*l] = ax; red[wid][2*l+1] = ay;
  __syncthreads();
  if (threadIdx.x < 128){
    int d = threadIdx.x;
    pooled[d] = (red[0][d] + red[1][d] + red[2][d] + red[3][d]) * (1.f/128.f);
  }
  __syncthreads();
  if (threadIdx.x < 64){
    int j = threadIdx.x;
    float s = b1[j];
    for (int d = 0; d < 128; d++) s += pooled[d] * w1[d*64 + j];
    h1s[j] = fmaxf(s, 0.f);
  }
  __syncthreads();
  if (threadIdx.x < 2){
    int j = threadIdx.x;
    float s = b2[j];
    for (int k = 0; k < 64; k++) s += h1s[k] * w2[k*2 + j];
    out[b*2 + j] = s;
  }
}

extern "C" void kernel_launch(void* const* d_in, const int* in_sizes, int n_in,
                              void* d_out, int out_size, void* d_ws, size_t ws_size,
                              hipStream_t stream){
  const int*   tok    = (const int*)d_in[0];
  const float* emb    = (const float*)d_in[1];
  const float* ln1_w  = (const float*)d_in[2];
  const float* conv_w = (const float*)d_in[3];
  const float* conv_b = (const float*)d_in[4];
  const float* Wi     = (const float*)d_in[5];
  const float* Wf     = (const float*)d_in[6];
  const float* Wz     = (const float*)d_in[7];
  const float* Wo     = (const float*)d_in[8];
  const float* Rk     = (const float*)d_in[9];
  const float* cell_b = (const float*)d_in[10];
  const float* gn_w   = (const float*)d_in[11];
  const float* ln2_w  = (const float*)d_in[12];
  const float* ff_w1  = (const float*)d_in[13];
  const float* ff_b1  = (const float*)d_in[14];
  const float* ff_w2  = (const float*)d_in[15];
  const float* ff_b2  = (const float*)d_in[16];
  const float* postw  = (const float*)d_in[17];
  const float* cw1    = (const float*)d_in[18];
  const float* cb1    = (const float*)d_in[19];
  const float* cw2    = (const float*)d_in[20];
  const float* cb2    = (const float*)d_in[21];
  float* out = (float*)d_out;

  char* ws = (char*)d_ws;
  size_t off = 0;
  float* x      = (float*)(ws + off); off += (size_t)BT*128*4;   // 33.55 MB
  u16*   xn_bf  = (u16*)(ws + off);   off += (size_t)BT*128*2;   // 16.78 MB
  u16*   xc_bf  = (u16*)(ws + off);   off += (size_t)BT*128*2;   // 16.78 MB
  u16*   gates  = (u16*)(ws + off);                              // 67.1 MB
  u16*   act    = gates;              off += (size_t)BT*512*2;   // act aliases gates (disjoint lifetime)
  u16*   w1T    = (u16*)(ws + off);   off += (size_t)NBB*384*128*2;
  u16*   w2T    = (u16*)(ws + off);   off += (size_t)NBB*128*192*2;
  u16*   gifT   = (u16*)(ws + off);   off += (size_t)NBB*HH*64*32*2;
  u16*   gzoT   = (u16*)(ws + off);   off += (size_t)NBB*HH*64*32*2;

  k_convert<<<704, 256, 0, stream>>>(ff_w1, ff_w2, Wi, Wf, Wz, Wo, w1T, w2T, gifT, gzoT);
  k_embed<<<(BT*32 + 255)/256, 256, 0, stream>>>(tok, emb, x);
  for (int nb = 0; nb < NBB; nb++){
    k_lnconv<<<BB*4, 256, 0, stream>>>(x, ln1_w, conv_w, conv_b, xn_bf, xc_bf, nb);
    k_gates<<<dim3(BT/64, HH, 2), 256, 0, stream>>>(xc_bf, xn_bf, gifT, gzoT, gates, nb);
    k_scan<<<512, 256, 0, stream>>>(gates, Rk, cell_b, gn_w, x, nb);
    k_ff1<<<BT/64, 256, 0, stream>>>(x, ln2_w, w1T, ff_b1, act, nb);
    k_ff2<<<BT/64, 256, 0, stream>>>(act, w2T, ff_b2, x, nb);
  }
  k_pool_cls<<<BB, 256, 0, stream>>>(x, postw, cw1, cb1, cw2, cb2, out);
}

// Round 3
// 533.588 us; speedup vs baseline: 1.0744x; 1.0744x over previous
//
#include <hip/hip_runtime.h>

typedef unsigned short u16;
typedef unsigned int u32;
typedef __attribute__((ext_vector_type(8))) short short8;
typedef __attribute__((ext_vector_type(4))) short s16x4;
typedef __attribute__((ext_vector_type(4))) float f32x4;
typedef __attribute__((ext_vector_type(2))) float f32x2;

#define BB 512
#define TT 128
#define DD 128
#define HH 4
#define NBB 2
#define BT (BB*TT)
#define EPSF 1e-5f
#define LOG2E 1.4426950408889634f

__device__ __forceinline__ float bf2f(u16 u){ return __uint_as_float(((u32)u) << 16); }
__device__ __forceinline__ u16 f2bf(float f){
  u32 x = __float_as_uint(f);
  u32 r = x + 0x7fffu + ((x >> 16) & 1u);
  return (u16)(r >> 16);
}
__device__ __forceinline__ float bcastf(float v, int lane){
  return __uint_as_float(__builtin_amdgcn_readlane(__float_as_uint(v), lane));
}
__device__ __forceinline__ float fast_tanh(float x){
  float ax = fabsf(x);
  float e = __expf(-2.f * ax);
  float t = (1.f - e) / (1.f + e);
  return copysignf(t, x);
}
__device__ __forceinline__ float gelu_tanh(float x){
  float u = 0.7978845608028654f * (x + 0.044715f * x * x * x);
  return 0.5f * x * (1.f + fast_tanh(u));
}
__device__ __forceinline__ float wredsum64(float v){
  #pragma unroll
  for (int m = 32; m; m >>= 1) v += __shfl_xor(v, m, 64);
  return v;
}

// ---------------- weight conversion to bf16 (transposed for MFMA B-frags) ----
__global__ __launch_bounds__(256) void k_convert(
    const float* __restrict__ ff_w1, const float* __restrict__ ff_w2,
    const float* __restrict__ Wi, const float* __restrict__ Wf,
    const float* __restrict__ Wz, const float* __restrict__ Wo,
    u16* __restrict__ w1T, u16* __restrict__ w2T,
    u16* __restrict__ gifT, u16* __restrict__ gzoT){
  int tid = blockIdx.x * 256 + threadIdx.x;
  const int n1 = NBB*384*128;
  if (tid < n1){
    int nb = tid / (384*128); int r = tid - nb*384*128; int n = r >> 7, k = r & 127;
    w1T[tid] = f2bf(ff_w1[(nb*128 + k)*384 + n]); return;
  }
  tid -= n1;
  const int n2 = NBB*128*192;
  if (tid < n2){
    int nb = tid / (128*192); int r = tid - nb*128*192; int n = r / 192, k = r - n*192;
    w2T[tid] = f2bf(ff_w2[(nb*192 + k)*128 + n]); return;
  }
  tid -= n2;
  const int n3 = NBB*HH*64*32;
  if (tid < n3){
    int nb = tid / (HH*64*32); int r = tid - nb*HH*64*32;
    int h = r >> 11; int r2 = r & 2047; int n = r2 >> 5, k = r2 & 31;
    const float* W = (n < 32) ? Wi : Wf; int nn = n & 31;
    gifT[tid] = f2bf(W[((nb*HH + h)*32 + k)*32 + nn]); return;
  }
  tid -= n3;
  if (tid < n3){
    int nb = tid / (HH*64*32); int r = tid - nb*HH*64*32;
    int h = r >> 11; int r2 = r & 2047; int n = r2 >> 5, k = r2 & 31;
    const float* W = (n < 32) ? Wz : Wo; int nn = n & 31;
    gzoT[tid] = f2bf(W[((nb*HH + h)*32 + k)*32 + nn]); return;
  }
}

// ---------------- embedding gather ----------------
__global__ __launch_bounds__(256) void k_embed(const int* __restrict__ tok,
                                               const float* __restrict__ emb,
                                               float* __restrict__ x){
  int tid = blockIdx.x * 256 + threadIdx.x;
  int row = tid >> 5, c = tid & 31;
  if (row < BT){
    ((f32x4*)x)[(size_t)row*32 + c] = ((const f32x4*)emb)[(size_t)tok[row]*32 + c];
  }
}

// ---------------- LN1 + causal depthwise conv + silu ----------------
__global__ __launch_bounds__(256) void k_lnconv(const float* __restrict__ x,
    const float* __restrict__ ln1_w, const float* __restrict__ conv_w,
    const float* __restrict__ conv_b, u16* __restrict__ xn_bf,
    u16* __restrict__ xc_bf, int nb){
  __shared__ float lnbuf[35][128];
  int b = blockIdx.x >> 2, tile = blockIdx.x & 3;
  int t0 = tile * 32;
  int wid = threadIdx.x >> 6, l = threadIdx.x & 63;
  for (int tt = wid; tt < 35; tt += 4){
    int t = t0 - 3 + tt;
    if (t < 0){
      lnbuf[tt][2*l] = 0.f; lnbuf[tt][2*l+1] = 0.f;
    } else {
      float2 v = ((const float2*)(x + (size_t)(b*TT + t)*128))[l];
      float s  = wredsum64(v.x + v.y);
      float sq = wredsum64(v.x*v.x + v.y*v.y);
      float mu = s * (1.f/128.f);
      float var = sq * (1.f/128.f) - mu*mu;
      float rs = rsqrtf(var + EPSF);
      float2 w = ((const float2*)(ln1_w + nb*128))[l];
      float y0 = (v.x - mu)*rs*w.x, y1 = (v.y - mu)*rs*w.y;
      lnbuf[tt][2*l] = y0; lnbuf[tt][2*l+1] = y1;
      if (tt >= 3){
        u32 pk = (u32)f2bf(y0) | ((u32)f2bf(y1) << 16);
        ((u32*)(xn_bf + (size_t)(b*TT + t)*128))[l] = pk;
      }
    }
  }
  __syncthreads();
  for (int e = threadIdx.x; e < 32*128; e += 256){
    int tt = e >> 7, d = e & 127;
    float s = conv_b[nb*128 + d];
    #pragma unroll
    for (int k = 0; k < 4; k++)
      s += lnbuf[tt + k][d] * conv_w[(nb*128 + d)*4 + k];
    float sig = 1.f / (1.f + __expf(-s));
    xc_bf[(size_t)(b*TT + t0 + tt)*128 + d] = f2bf(s * sig);
  }
}

// ---------------- gate projections (MFMA), t-major output ----------------
// gates layout: [b][h][col(128)][T]  where col = z*64 + (i|f or z|o slot)
__global__ __launch_bounds__(256) void k_gates(const u16* __restrict__ xc_bf,
    const u16* __restrict__ xn_bf, const u16* __restrict__ gifT,
    const u16* __restrict__ gzoT, u16* __restrict__ gates, int nb){
  int m0 = blockIdx.x * 64;
  int b = m0 >> 7;
  int t00 = m0 & 127;
  int h = blockIdx.y, z = blockIdx.z;
  int wid = threadIdx.x >> 6, l = threadIdx.x & 63;
  const u16* A  = z ? xn_bf : xc_bf;
  const u16* Bw = (z ? gzoT : gifT) + (size_t)(nb*HH + h)*64*32;
  int r0 = m0 + wid*16;
  short8 a = *(const short8*)(A + (size_t)(r0 + (l & 15))*128 + h*32 + (l >> 4)*8);
  #pragma unroll
  for (int jt = 0; jt < 4; jt++){
    f32x4 acc = {0.f, 0.f, 0.f, 0.f};
    short8 bf = *(const short8*)(Bw + (jt*16 + (l & 15))*32 + (l >> 4)*8);
    acc = __builtin_amdgcn_mfma_f32_16x16x32_bf16(a, bf, acc, 0, 0, 0);
    int cloc = z*64 + jt*16 + (l & 15);
    int tt = t00 + wid*16 + (l >> 4)*4;
    s16x4 pk;
    #pragma unroll
    for (int r = 0; r < 4; r++) pk[r] = (short)f2bf(acc[r]);
    *(s16x4*)(gates + ((size_t)(b*HH + h)*128 + cloc)*TT + tt) = pk;
  }
}

// ---------------- sLSTM recurrent scan + group-norm + residual ----------------
// one wave per (batch, head); lane l owns gate columns l and l+64 (packed f32x2)
__global__ __launch_bounds__(256) void k_scan(const u16* __restrict__ gates,
    const float* __restrict__ Rk, const float* __restrict__ cell_b,
    const float* __restrict__ gn_w, float* __restrict__ x, int nb){
  int wid = threadIdx.x >> 6, l = threadIdx.x & 63;
  int pair = blockIdx.x * 4 + wid;       // 2048 chains
  int b = pair >> 2, h = pair & 3;
  f32x2 rk[32];
  const float* Rkh = Rk + (size_t)(nb*HH + h)*32*128;
  #pragma unroll
  for (int d = 0; d < 32; d++){
    rk[d].x = Rkh[d*128 + l];
    rk[d].y = Rkh[d*128 + l + 64];
  }
  f32x2 cb = { cell_b[(nb*HH + h)*128 + l], cell_b[(nb*HH + h)*128 + l + 64] };
  int e = l & 31;
  bool lo = (l < 32);
  float gnw = gn_w[nb*128 + h*32 + e];
  float hs = 0.f, cs = 0.f, ns = 0.f, ms = 0.f;
  const u16* gp0 = gates + ((size_t)(b*HH + h)*128 + l)*TT;   // col l, t-major
  const u16* gp1 = gp0 + (size_t)64*TT;                        // col l+64
  float* xpb = x + (size_t)(b*TT)*128 + h*32 + e;              // per-lane residual addr
  float xnext = lo ? xpb[0] : 0.f;
  short8 ga = *(const short8*)gp0;
  short8 gb = *(const short8*)gp1;
  for (int t8 = 0; t8 < 16; t8++){
    // prefetch next 8 steps' gates (overreads 16B past column at t8=15; ws-mapped)
    short8 na  = *(const short8*)(gp0 + (t8+1)*8);
    short8 nb2 = *(const short8*)(gp1 + (t8+1)*8);
    #pragma unroll
    for (int k = 0; k < 8; k++){
      int t = t8*8 + k;
      float xcur = xnext;
      if (lo) xnext = xpb[(t+1)*128];     // prefetch next residual (overread ok)
      f32x2 acc0 = { bf2f((u16)ga[k]) + cb.x, bf2f((u16)gb[k]) + cb.y };
      f32x2 acc1 = {0.f, 0.f}, acc2 = {0.f, 0.f}, acc3 = {0.f, 0.f};
      #pragma unroll
      for (int d = 0; d < 32; d += 4){
        float h0 = bcastf(hs, d),   h1 = bcastf(hs, d+1);
        float h2 = bcastf(hs, d+2), h3 = bcastf(hs, d+3);
        acc0 = __builtin_elementwise_fma((f32x2){h0,h0}, rk[d],   acc0);
        acc1 = __builtin_elementwise_fma((f32x2){h1,h1}, rk[d+1], acc1);
        acc2 = __builtin_elementwise_fma((f32x2){h2,h2}, rk[d+2], acc2);
        acc3 = __builtin_elementwise_fma((f32x2){h3,h3}, rk[d+3], acc3);
      }
      f32x2 rr = (acc0 + acc1) + (acc2 + acc3);
      float r0 = rr.x, r1 = rr.y;
      float fx = __shfl_xor(r0, 32, 64);   // lanes<32: fr[e]; lanes>=32: ir[e]
      float ox = __shfl_xor(r1, 32, 64);   // lanes<32: og[e]
      // lanes<32: r0=ir, r1=zr
      float mnew = fmaxf(fx + ms, r0);
      float ig = __builtin_amdgcn_exp2f((r0 - mnew) * LOG2E);
      float fg = __builtin_amdgcn_exp2f((fx + ms - mnew) * LOG2E);
      // tanh(r1) = 1 - 2*rcp(exp2(2*log2e*r1)+1); saturates correctly at +/-inf
      float e2 = __builtin_amdgcn_exp2f(2.f * LOG2E * r1);
      float th = fmaf(-2.f, __builtin_amdgcn_rcpf(e2 + 1.f), 1.f);
      cs = fmaf(fg, cs, ig * th);
      ns = fmaf(fg, ns, ig);
      ms = mnew;
      float sg = __builtin_amdgcn_rcpf(1.f + __builtin_amdgcn_exp2f(-ox * LOG2E));
      hs = cs * __builtin_amdgcn_rcpf(ns) * sg;
      // group norm over 32 head dims (lanes 0..31 hold them) -- off critical path
      float s = hs, sq = hs*hs;
      #pragma unroll
      for (int m = 16; m; m >>= 1){
        s  += __shfl_xor(s,  m, 64);
        sq += __shfl_xor(sq, m, 64);
      }
      float mu = s * (1.f/32.f);
      float var = sq * (1.f/32.f) - mu*mu;
      float yn = (hs - mu) * __builtin_amdgcn_rsqf(var + EPSF) * gnw;
      if (lo) xpb[t*128] = xcur + yn;
    }
    ga = na; gb = nb2;
  }
}

// ---------------- LN2 + FFN up-proj + gelu*up (MFMA) ----------------
__global__ __launch_bounds__(256) void k_ff1(const float* __restrict__ x,
    const float* __restrict__ ln2_w, const u16* __restrict__ w1T,
    const float* __restrict__ ff_b1, u16* __restrict__ act, int nb){
  __shared__ u16 lnb[64][128];
  int m0 = blockIdx.x * 64;
  int wid = threadIdx.x >> 6, l = threadIdx.x & 63;
  float2 w = ((const float2*)(ln2_w + nb*128))[l];
  for (int rr = 0; rr < 16; rr++){
    int row = wid*16 + rr;
    float2 v = ((const float2*)(x + (size_t)(m0 + row)*128))[l];
    float s  = wredsum64(v.x + v.y);
    float sq = wredsum64(v.x*v.x + v.y*v.y);
    float mu = s * (1.f/128.f);
    float var = sq * (1.f/128.f) - mu*mu;
    float rs = rsqrtf(var + EPSF);
    float y0 = (v.x - mu)*rs*w.x, y1 = (v.y - mu)*rs*w.y;
    ((u32*)lnb[row])[l] = (u32)f2bf(y0) | ((u32)f2bf(y1) << 16);
  }
  __syncthreads();
  short8 a[4];
  #pragma unroll
  for (int c = 0; c < 4; c++)
    a[c] = *(const short8*)(&lnb[wid*16 + (l & 15)][c*32 + (l >> 4)*8]);
  const u16* W = w1T + (size_t)nb*384*128;
  f32x4 acc[24];
  #pragma unroll
  for (int jt = 0; jt < 24; jt++){
    acc[jt] = {0.f, 0.f, 0.f, 0.f};
    #pragma unroll
    for (int c = 0; c < 4; c++){
      short8 bf = *(const short8*)(W + (size_t)(jt*16 + (l & 15))*128 + c*32 + (l >> 4)*8);
      acc[jt] = __builtin_amdgcn_mfma_f32_16x16x32_bf16(a[c], bf, acc[jt], 0, 0, 0);
    }
  }
  #pragma unroll
  for (int jt = 0; jt < 12; jt++){
    int colg = jt*16 + (l & 15);
    float bg = ff_b1[nb*384 + colg];
    float bu = ff_b1[nb*384 + 192 + colg];
    #pragma unroll
    for (int r = 0; r < 4; r++){
      int row = m0 + wid*16 + (l >> 4)*4 + r;
      float gh = acc[jt][r] + bg;
      float uh = acc[jt + 12][r] + bu;
      act[(size_t)row*192 + colg] = f2bf(gelu_tanh(gh) * uh);
    }
  }
}

// ---------------- FFN down-proj + residual (MFMA) ----------------
__global__ __launch_bounds__(256) void k_ff2(const u16* __restrict__ act,
    const u16* __restrict__ w2T, const float* __restrict__ ff_b2,
    float* __restrict__ x, int nb){
  int m0 = blockIdx.x * 64;
  int wid = threadIdx.x >> 6, l = threadIdx.x & 63;
  short8 a[6];
  #pragma unroll
  for (int c = 0; c < 6; c++)
    a[c] = *(const short8*)(act + (size_t)(m0 + wid*16 + (l & 15))*192 + c*32 + (l >> 4)*8);
  const u16* W = w2T + (size_t)nb*128*192;
  #pragma unroll
  for (int jt = 0; jt < 8; jt++){
    f32x4 acc = {0.f, 0.f, 0.f, 0.f};
    #pragma unroll
    for (int c = 0; c < 6; c++){
      short8 bf = *(const short8*)(W + (size_t)(jt*16 + (l & 15))*192 + c*32 + (l >> 4)*8);
      acc = __builtin_amdgcn_mfma_f32_16x16x32_bf16(a[c], bf, acc, 0, 0, 0);
    }
    int col = jt*16 + (l & 15);
    float bias = ff_b2[nb*128 + col];
    #pragma unroll
    for (int r = 0; r < 4; r++){
      int row = m0 + wid*16 + (l >> 4)*4 + r;
      x[(size_t)row*128 + col] += acc[r] + bias;
    }
  }
}

// ---------------- post-LN + mean-pool + classifier ----------------
__global__ __launch_bounds__(256) void k_pool_cls(const float* __restrict__ x,
    const float* __restrict__ pw, const float* __restrict__ w1,
    const float* __restrict__ b1, const float* __restrict__ w2,
    const float* __restrict__ b2, float* __restrict__ out){
  __shared__ float red[4][128];
  __shared__ float pooled[128];
  __shared__ float h1s[64];
  int b = blockIdx.x;
  int wid = threadIdx.x >> 6, l = threadIdx.x & 63;
  float2 w = ((const float2*)pw)[l];
  float ax = 0.f, ay = 0.f;
  for (int t = wid; t < TT; t += 4){
    float2 v = ((const float2*)(x + (size_t)(b*TT + t)*128))[l];
    float s  = wredsum64(v.x + v.y);
    float sq = wredsum64(v.x*v.x + v.y*v.y);
    float mu = s * (1.f/128.f);
    float var = sq * (1.f/128.f) - mu*mu;
    float rs = rsqrtf(var + EPSF);
    ax += (v.x - mu)*rs*w.x;
    ay += (v.y - mu)*rs*w.y;
  }
  red[wid][2*l] = ax; red[wid][2*l+1] = ay;
  __syncthreads();
  if (threadIdx.x < 128){
    int d = threadIdx.x;
    pooled[d] = (red[0][d] + red[1][d] + red[2][d] + red[3][d]) * (1.f/128.f);
  }
  __syncthreads();
  if (threadIdx.x < 64){
    int j = threadIdx.x;
    float s = b1[j];
    for (int d = 0; d < 128; d++) s += pooled[d] * w1[d*64 + j];
    h1s[j] = fmaxf(s, 0.f);
  }
  __syncthreads();
  if (threadIdx.x < 2){
    int j = threadIdx.x;
    float s = b2[j];
    for (int k = 0; k < 64; k++) s += h1s[k] * w2[k*2 + j];
    out[b*2 + j] = s;
  }
}

extern "C" void kernel_launch(void* const* d_in, const int* in_sizes, int n_in,
                              void* d_out, int out_size, void* d_ws, size_t ws_size,
                              hipStream_t stream){
  const int*   tok    = (const int*)d_in[0];
  const float* emb    = (const float*)d_in[1];
  const float* ln1_w  = (const float*)d_in[2];
  const float* conv_w = (const float*)d_in[3];
  const float* conv_b = (const float*)d_in[4];
  const float* Wi     = (const float*)d_in[5];
  const float* Wf     = (const float*)d_in[6];
  const float* Wz     = (const float*)d_in[7];
  const float* Wo     = (const float*)d_in[8];
  const float* Rk     = (const float*)d_in[9];
  const float* cell_b = (const float*)d_in[10];
  const float* gn_w   = (const float*)d_in[11];
  const float* ln2_w  = (const float*)d_in[12];
  const float* ff_w1  = (const float*)d_in[13];
  const float* ff_b1  = (const float*)d_in[14];
  const float* ff_w2  = (const float*)d_in[15];
  const float* ff_b2  = (const float*)d_in[16];
  const float* postw  = (const float*)d_in[17];
  const float* cw1    = (const float*)d_in[18];
  const float* cb1    = (const float*)d_in[19];
  const float* cw2    = (const float*)d_in[20];
  const float* cb2    = (const float*)d_in[21];
  float* out = (float*)d_out;

  char* ws = (char*)d_ws;
  size_t off = 0;
  float* x      = (float*)(ws + off); off += (size_t)BT*128*4;
  u16*   xn_bf  = (u16*)(ws + off);   off += (size_t)BT*128*2;
  u16*   xc_bf  = (u16*)(ws + off);   off += (size_t)BT*128*2;
  u16*   gates  = (u16*)(ws + off);
  u16*   act    = gates;              off += (size_t)BT*512*2;   // act aliases gates
  u16*   w1T    = (u16*)(ws + off);   off += (size_t)NBB*384*128*2;
  u16*   w2T    = (u16*)(ws + off);   off += (size_t)NBB*128*192*2;
  u16*   gifT   = (u16*)(ws + off);   off += (size_t)NBB*HH*64*32*2;
  u16*   gzoT   = (u16*)(ws + off);   off += (size_t)NBB*HH*64*32*2;

  k_convert<<<704, 256, 0, stream>>>(ff_w1, ff_w2, Wi, Wf, Wz, Wo, w1T, w2T, gifT, gzoT);
  k_embed<<<(BT*32 + 255)/256, 256, 0, stream>>>(tok, emb, x);
  for (int nb = 0; nb < NBB; nb++){
    k_lnconv<<<BB*4, 256, 0, stream>>>(x, ln1_w, conv_w, conv_b, xn_bf, xc_bf, nb);
    k_gates<<<dim3(BT/64, HH, 2), 256, 0, stream>>>(xc_bf, xn_bf, gifT, gzoT, gates, nb);
    k_scan<<<512, 256, 0, stream>>>(gates, Rk, cell_b, gn_w, x, nb);
    k_ff1<<<BT/64, 256, 0, stream>>>(x, ln2_w, w1T, ff_b1, act, nb);
    k_ff2<<<BT/64, 256, 0, stream>>>(act, w2T, ff_b2, x, nb);
  }
  k_pool_cls<<<BB, 256, 0, stream>>>(x, postw, cw1, cb1, cw2, cb2, out);
}

// Round 5
// 479.354 us; speedup vs baseline: 1.1960x; 1.1131x over previous
//
#include <hip/hip_runtime.h>

typedef unsigned short u16;
typedef unsigned int u32;
typedef __attribute__((ext_vector_type(8))) short short8;
typedef __attribute__((ext_vector_type(4))) short s16x4;
typedef __attribute__((ext_vector_type(4))) float f32x4;
typedef __attribute__((ext_vector_type(2))) float f32x2;
typedef __attribute__((ext_vector_type(2))) int i32x2;

#define BB 512
#define TT 128
#define DD 128
#define HH 4
#define NBB 2
#define BT (BB*TT)
#define EPSF 1e-5f
#define LOG2E 1.4426950408889634f

__device__ __forceinline__ float bf2f(u16 u){ return __uint_as_float(((u32)u) << 16); }
__device__ __forceinline__ u16 f2bf(float f){
  u32 x = __float_as_uint(f);
  u32 r = x + 0x7fffu + ((x >> 16) & 1u);
  return (u16)(r >> 16);
}
__device__ __forceinline__ float bcastf(float v, int lane){
  return __uint_as_float(__builtin_amdgcn_readlane(__float_as_uint(v), lane));
}
__device__ __forceinline__ float fast_tanh(float x){
  float ax = fabsf(x);
  float e = __expf(-2.f * ax);
  float t = (1.f - e) / (1.f + e);
  return copysignf(t, x);
}
__device__ __forceinline__ float gelu_tanh(float x){
  float u = 0.7978845608028654f * (x + 0.044715f * x * x * x);
  return 0.5f * x * (1.f + fast_tanh(u));
}
__device__ __forceinline__ float wredsum64(float v){
  #pragma unroll
  for (int m = 32; m; m >>= 1) v += __shfl_xor(v, m, 64);
  return v;
}
// DPP add helper: v += dpp_move(v); masked/OOB lanes add 0 (old=0 either mode).
#define DPP_ADD(v, ctrl, rmask, bc) \
  v += __int_as_float(__builtin_amdgcn_update_dpp(0, __float_as_int(v), (ctrl), (rmask), 0xf, (bc)))
// sum over lanes 0..31; total lands in lane 31 (lane 63 gets sum of 32..63, unused)
__device__ __forceinline__ float rsum_rows01(float v){
  DPP_ADD(v, 0x111, 0xf, true);   // row_shr:1
  DPP_ADD(v, 0x112, 0xf, true);   // row_shr:2
  DPP_ADD(v, 0x114, 0xf, true);   // row_shr:4
  DPP_ADD(v, 0x118, 0xf, true);   // row_shr:8  -> lane15/31 hold row sums
  DPP_ADD(v, 0x142, 0xa, false);  // row_bcast:15 into rows 1,3 -> lane31 = total(0..31)
  return v;
}
// lanes<32 receive v from lane+32 (VALU permlane32_swap; no LDS). Upper lanes: own value.
__device__ __forceinline__ float down32(float v){
  i32x2 r = __builtin_amdgcn_permlane32_swap(__float_as_int(v), __float_as_int(v), false, false);
  return __int_as_float(r.y);   // new_vsrc = {old.hi -> lanes0..31, old.hi}
}

// ---------------- weight conversion to bf16 (transposed for MFMA B-frags) ----
__global__ __launch_bounds__(256) void k_convert(
    const float* __restrict__ ff_w1, const float* __restrict__ ff_w2,
    const float* __restrict__ Wi, const float* __restrict__ Wf,
    const float* __restrict__ Wz, const float* __restrict__ Wo,
    u16* __restrict__ w1T, u16* __restrict__ w2T,
    u16* __restrict__ gifT, u16* __restrict__ gzoT){
  int tid = blockIdx.x * 256 + threadIdx.x;
  const int n1 = NBB*384*128;
  if (tid < n1){
    int nb = tid / (384*128); int r = tid - nb*384*128; int n = r >> 7, k = r & 127;
    w1T[tid] = f2bf(ff_w1[(nb*128 + k)*384 + n]); return;
  }
  tid -= n1;
  const int n2 = NBB*128*192;
  if (tid < n2){
    int nb = tid / (128*192); int r = tid - nb*128*192; int n = r / 192, k = r - n*192;
    w2T[tid] = f2bf(ff_w2[(nb*192 + k)*128 + n]); return;
  }
  tid -= n2;
  const int n3 = NBB*HH*64*32;
  if (tid < n3){
    int nb = tid / (HH*64*32); int r = tid - nb*HH*64*32;
    int h = r >> 11; int r2 = r & 2047; int n = r2 >> 5, k = r2 & 31;
    const float* W = (n < 32) ? Wi : Wf; int nn = n & 31;
    gifT[tid] = f2bf(W[((nb*HH + h)*32 + k)*32 + nn]); return;
  }
  tid -= n3;
  if (tid < n3){
    int nb = tid / (HH*64*32); int r = tid - nb*HH*64*32;
    int h = r >> 11; int r2 = r & 2047; int n = r2 >> 5, k = r2 & 31;
    const float* W = (n < 32) ? Wz : Wo; int nn = n & 31;
    gzoT[tid] = f2bf(W[((nb*HH + h)*32 + k)*32 + nn]); return;
  }
}

// ---------------- embedding gather ----------------
__global__ __launch_bounds__(256) void k_embed(const int* __restrict__ tok,
                                               const float* __restrict__ emb,
                                               float* __restrict__ x){
  int tid = blockIdx.x * 256 + threadIdx.x;
  int row = tid >> 5, c = tid & 31;
  if (row < BT){
    ((f32x4*)x)[(size_t)row*32 + c] = ((const f32x4*)emb)[(size_t)tok[row]*32 + c];
  }
}

// ---------------- LN1 + causal depthwise conv + silu ----------------
__global__ __launch_bounds__(256) void k_lnconv(const float* __restrict__ x,
    const float* __restrict__ ln1_w, const float* __restrict__ conv_w,
    const float* __restrict__ conv_b, u16* __restrict__ xn_bf,
    u16* __restrict__ xc_bf, int nb){
  __shared__ float lnbuf[35][128];
  int b = blockIdx.x >> 2, tile = blockIdx.x & 3;
  int t0 = tile * 32;
  int wid = threadIdx.x >> 6, l = threadIdx.x & 63;
  for (int tt = wid; tt < 35; tt += 4){
    int t = t0 - 3 + tt;
    if (t < 0){
      lnbuf[tt][2*l] = 0.f; lnbuf[tt][2*l+1] = 0.f;
    } else {
      float2 v = ((const float2*)(x + (size_t)(b*TT + t)*128))[l];
      float s  = wredsum64(v.x + v.y);
      float sq = wredsum64(v.x*v.x + v.y*v.y);
      float mu = s * (1.f/128.f);
      float var = sq * (1.f/128.f) - mu*mu;
      float rs = rsqrtf(var + EPSF);
      float2 w = ((const float2*)(ln1_w + nb*128))[l];
      float y0 = (v.x - mu)*rs*w.x, y1 = (v.y - mu)*rs*w.y;
      lnbuf[tt][2*l] = y0; lnbuf[tt][2*l+1] = y1;
      if (tt >= 3){
        u32 pk = (u32)f2bf(y0) | ((u32)f2bf(y1) << 16);
        ((u32*)(xn_bf + (size_t)(b*TT + t)*128))[l] = pk;
      }
    }
  }
  __syncthreads();
  for (int e = threadIdx.x; e < 32*128; e += 256){
    int tt = e >> 7, d = e & 127;
    float s = conv_b[nb*128 + d];
    #pragma unroll
    for (int k = 0; k < 4; k++)
      s += lnbuf[tt + k][d] * conv_w[(nb*128 + d)*4 + k];
    float sig = 1.f / (1.f + __expf(-s));
    xc_bf[(size_t)(b*TT + t0 + tt)*128 + d] = f2bf(s * sig);
  }
}

// ---------------- gate projections (MFMA) ----------------
// gates layout: [b][h][t>>3][col(128)][t&7]  (16B per (t8,col) group, wave-coalesced)
__global__ __launch_bounds__(256) void k_gates(const u16* __restrict__ xc_bf,
    const u16* __restrict__ xn_bf, const u16* __restrict__ gifT,
    const u16* __restrict__ gzoT, u16* __restrict__ gates, int nb){
  int m0 = blockIdx.x * 64;
  int b = m0 >> 7;
  int t00 = m0 & 127;
  int h = blockIdx.y, z = blockIdx.z;
  int wid = threadIdx.x >> 6, l = threadIdx.x & 63;
  const u16* A  = z ? xn_bf : xc_bf;
  const u16* Bw = (z ? gzoT : gifT) + (size_t)(nb*HH + h)*64*32;
  int r0 = m0 + wid*16;
  short8 a = *(const short8*)(A + (size_t)(r0 + (l & 15))*128 + h*32 + (l >> 4)*8);
  u16* gb = gates + (size_t)(b*HH + h)*TT*128;
  #pragma unroll
  for (int jt = 0; jt < 4; jt++){
    f32x4 acc = {0.f, 0.f, 0.f, 0.f};
    short8 bf = *(const short8*)(Bw + (jt*16 + (l & 15))*32 + (l >> 4)*8);
    acc = __builtin_amdgcn_mfma_f32_16x16x32_bf16(a, bf, acc, 0, 0, 0);
    int cloc = z*64 + jt*16 + (l & 15);
    int tt = t00 + wid*16 + (l >> 4)*4;          // 4-aligned
    s16x4 pk;
    #pragma unroll
    for (int r = 0; r < 4; r++) pk[r] = (short)f2bf(acc[r]);
    *(s16x4*)(gb + ((size_t)(tt >> 3)*128 + cloc)*8 + (tt & 7)) = pk;
  }
}

// ---------------- sLSTM recurrent scan + group-norm + residual ----------------
// one wave per (batch, head); lane l owns gate cols l and l+64.
// lanes<32: (ir, zr); lanes>=32: (fr, og). NO LDS/DS ops in the loop.
__global__ __launch_bounds__(256) void k_scan(const u16* __restrict__ gates,
    const float* __restrict__ Rk, const float* __restrict__ cell_b,
    const float* __restrict__ gn_w, float* __restrict__ x, int nb){
  int wid = threadIdx.x >> 6, l = threadIdx.x & 63;
  int pair = blockIdx.x * 4 + wid;       // 2048 chains
  int b = pair >> 2, h = pair & 3;
  f32x2 rk[32];
  const float* Rkh = Rk + (size_t)(nb*HH + h)*32*128;
  #pragma unroll
  for (int d = 0; d < 32; d++){
    rk[d].x = Rkh[d*128 + l];
    rk[d].y = Rkh[d*128 + l + 64];
  }
  f32x2 cb = { cell_b[(nb*HH + h)*128 + l], cell_b[(nb*HH + h)*128 + l + 64] };
  int e = l & 31;
  bool lo = (l < 32);
  float gnw = gn_w[nb*128 + h*32 + e];
  float hs = 0.f, cs = 0.f, ns = 0.f, ms = 0.f;
  const u16* gbase = gates + (size_t)(b*HH + h)*TT*128;
  float* xpb = x + (size_t)(b*TT)*128 + h*32 + e;
  float xnext = lo ? xpb[0] : 0.f;
  short8 ga = *(const short8*)(gbase + (size_t)l*8);
  short8 gb = *(const short8*)(gbase + (size_t)(l + 64)*8);
  for (int t8 = 0; t8 < 16; t8++){
    // prefetch next 8 steps (1KB-coalesced per wave; overreads into next chunk at end — ws mapped)
    short8 na  = *(const short8*)(gbase + ((size_t)(t8+1)*128 + l)*8);
    short8 nb2 = *(const short8*)(gbase + ((size_t)(t8+1)*128 + l + 64)*8);
    #pragma unroll
    for (int k = 0; k < 8; k++){
      int t = t8*8 + k;
      float xcur = xnext;
      if (lo) xnext = xpb[(t+1)*128];     // prefetch next residual (overread ok)
      f32x2 acc0 = { bf2f((u16)ga[k]) + cb.x, bf2f((u16)gb[k]) + cb.y };
      f32x2 acc1 = {0.f, 0.f}, acc2 = {0.f, 0.f}, acc3 = {0.f, 0.f};
      #pragma unroll
      for (int d = 0; d < 32; d += 4){
        float h0 = bcastf(hs, d),   h1 = bcastf(hs, d+1);
        float h2 = bcastf(hs, d+2), h3 = bcastf(hs, d+3);
        acc0 = __builtin_elementwise_fma((f32x2){h0,h0}, rk[d],   acc0);
        acc1 = __builtin_elementwise_fma((f32x2){h1,h1}, rk[d+1], acc1);
        acc2 = __builtin_elementwise_fma((f32x2){h2,h2}, rk[d+2], acc2);
        acc3 = __builtin_elementwise_fma((f32x2){h3,h3}, rk[d+3], acc3);
      }
      f32x2 rr = (acc0 + acc1) + (acc2 + acc3);
      float r0 = rr.x, r1 = rr.y;          // lanes<32: ir, zr ; lanes>=32: fr, og
      float fx = down32(r0);               // lanes<32 get fr[e]   (VALU permlane)
      float ox = down32(r1);               // lanes<32 get og[e]
      // gating — valid in lanes<32; upper lanes compute garbage (never read)
      float mnew = fmaxf(fx + ms, r0);
      float ig = __builtin_amdgcn_exp2f((r0 - mnew) * LOG2E);
      float fg = __builtin_amdgcn_exp2f((fx + ms - mnew) * LOG2E);
      float e2 = __builtin_amdgcn_exp2f(2.f * LOG2E * r1);
      float th = fmaf(-2.f, __builtin_amdgcn_rcpf(e2 + 1.f), 1.f);   // tanh(zr)
      cs = fmaf(fg, cs, ig * th);
      ns = fmaf(fg, ns, ig);
      ms = mnew;
      float sg = __builtin_amdgcn_rcpf(1.f + __builtin_amdgcn_exp2f(-ox * LOG2E));
      hs = cs * __builtin_amdgcn_rcpf(ns) * sg;
      // group norm over lanes 0..31 via DPP (no LDS)
      float s = rsum_rows01(hs);
      float sq = rsum_rows01(hs * hs);
      float mu = bcastf(s, 31) * (1.f/32.f);
      float var = bcastf(sq, 31) * (1.f/32.f) - mu*mu;
      float yn = (hs - mu) * __builtin_amdgcn_rsqf(var + EPSF) * gnw;
      if (lo) xpb[t*128] = xcur + yn;
    }
    ga = na; gb = nb2;
  }
}

// ---------------- LN2 + FFN up-proj + gelu*up (MFMA) ----------------
__global__ __launch_bounds__(256) void k_ff1(const float* __restrict__ x,
    const float* __restrict__ ln2_w, const u16* __restrict__ w1T,
    const float* __restrict__ ff_b1, u16* __restrict__ act, int nb){
  __shared__ u16 lnb[64][128];
  int m0 = blockIdx.x * 64;
  int wid = threadIdx.x >> 6, l = threadIdx.x & 63;
  float2 w = ((const float2*)(ln2_w + nb*128))[l];
  for (int rr = 0; rr < 16; rr++){
    int row = wid*16 + rr;
    float2 v = ((const float2*)(x + (size_t)(m0 + row)*128))[l];
    float s  = wredsum64(v.x + v.y);
    float sq = wredsum64(v.x*v.x + v.y*v.y);
    float mu = s * (1.f/128.f);
    float var = sq * (1.f/128.f) - mu*mu;
    float rs = rsqrtf(var + EPSF);
    float y0 = (v.x - mu)*rs*w.x, y1 = (v.y - mu)*rs*w.y;
    ((u32*)lnb[row])[l] = (u32)f2bf(y0) | ((u32)f2bf(y1) << 16);
  }
  __syncthreads();
  short8 a[4];
  #pragma unroll
  for (int c = 0; c < 4; c++)
    a[c] = *(const short8*)(&lnb[wid*16 + (l & 15)][c*32 + (l >> 4)*8]);
  const u16* W = w1T + (size_t)nb*384*128;
  f32x4 acc[24];
  #pragma unroll
  for (int jt = 0; jt < 24; jt++){
    acc[jt] = {0.f, 0.f, 0.f, 0.f};
    #pragma unroll
    for (int c = 0; c < 4; c++){
      short8 bf = *(const short8*)(W + (size_t)(jt*16 + (l & 15))*128 + c*32 + (l >> 4)*8);
      acc[jt] = __builtin_amdgcn_mfma_f32_16x16x32_bf16(a[c], bf, acc[jt], 0, 0, 0);
    }
  }
  #pragma unroll
  for (int jt = 0; jt < 12; jt++){
    int colg = jt*16 + (l & 15);
    float bg = ff_b1[nb*384 + colg];
    float bu = ff_b1[nb*384 + 192 + colg];
    #pragma unroll
    for (int r = 0; r < 4; r++){
      int row = m0 + wid*16 + (l >> 4)*4 + r;
      float gh = acc[jt][r] + bg;
      float uh = acc[jt + 12][r] + bu;
      act[(size_t)row*192 + colg] = f2bf(gelu_tanh(gh) * uh);
    }
  }
}

// ---------------- FFN down-proj + residual (MFMA) ----------------
__global__ __launch_bounds__(256) void k_ff2(const u16* __restrict__ act,
    const u16* __restrict__ w2T, const float* __restrict__ ff_b2,
    float* __restrict__ x, int nb){
  int m0 = blockIdx.x * 64;
  int wid = threadIdx.x >> 6, l = threadIdx.x & 63;
  short8 a[6];
  #pragma unroll
  for (int c = 0; c < 6; c++)
    a[c] = *(const short8*)(act + (size_t)(m0 + wid*16 + (l & 15))*192 + c*32 + (l >> 4)*8);
  const u16* W = w2T + (size_t)nb*128*192;
  #pragma unroll
  for (int jt = 0; jt < 8; jt++){
    f32x4 acc = {0.f, 0.f, 0.f, 0.f};
    #pragma unroll
    for (int c = 0; c < 6; c++){
      short8 bf = *(const short8*)(W + (size_t)(jt*16 + (l & 15))*192 + c*32 + (l >> 4)*8);
      acc = __builtin_amdgcn_mfma_f32_16x16x32_bf16(a[c], bf, acc, 0, 0, 0);
    }
    int col = jt*16 + (l & 15);
    float bias = ff_b2[nb*128 + col];
    #pragma unroll
    for (int r = 0; r < 4; r++){
      int row = m0 + wid*16 + (l >> 4)*4 + r;
      x[(size_t)row*128 + col] += acc[r] + bias;
    }
  }
}

// ---------------- post-LN + mean-pool + classifier ----------------
__global__ __launch_bounds__(256) void k_pool_cls(const float* __restrict__ x,
    const float* __restrict__ pw, const float* __restrict__ w1,
    const float* __restrict__ b1, const float* __restrict__ w2,
    const float* __restrict__ b2, float* __restrict__ out){
  __shared__ float red[4][128];
  __shared__ float pooled[128];
  __shared__ float h1s[64];
  int b = blockIdx.x;
  int wid = threadIdx.x >> 6, l = threadIdx.x & 63;
  float2 w = ((const float2*)pw)[l];
  float ax = 0.f, ay = 0.f;
  for (int t = wid; t < TT; t += 4){
    float2 v = ((const float2*)(x + (size_t)(b*TT + t)*128))[l];
    float s  = wredsum64(v.x + v.y);
    float sq = wredsum64(v.x*v.x + v.y*v.y);
    float mu = s * (1.f/128.f);
    float var = sq * (1.f/128.f) - mu*mu;
    float rs = rsqrtf(var + EPSF);
    ax += (v.x - mu)*rs*w.x;
    ay += (v.y - mu)*rs*w.y;
  }
  red[wid][2*l] = ax; red[wid][2*l+1] = ay;
  __syncthreads();
  if (threadIdx.x < 128){
    int d = threadIdx.x;
    pooled[d] = (red[0][d] + red[1][d] + red[2][d] + red[3][d]) * (1.f/128.f);
  }
  __syncthreads();
  if (threadIdx.x < 64){
    int j = threadIdx.x;
    float s = b1[j];
    for (int d = 0; d < 128; d++) s += pooled[d] * w1[d*64 + j];
    h1s[j] = fmaxf(s, 0.f);
  }
  __syncthreads();
  if (threadIdx.x < 2){
    int j = threadIdx.x;
    float s = b2[j];
    for (int k = 0; k < 64; k++) s += h1s[k] * w2[k*2 + j];
    out[b*2 + j] = s;
  }
}

extern "C" void kernel_launch(void* const* d_in, const int* in_sizes, int n_in,
                              void* d_out, int out_size, void* d_ws, size_t ws_size,
                              hipStream_t stream){
  const int*   tok    = (const int*)d_in[0];
  const float* emb    = (const float*)d_in[1];
  const float* ln1_w  = (const float*)d_in[2];
  const float* conv_w = (const float*)d_in[3];
  const float* conv_b = (const float*)d_in[4];
  const float* Wi     = (const float*)d_in[5];
  const float* Wf     = (const float*)d_in[6];
  const float* Wz     = (const float*)d_in[7];
  const float* Wo     = (const float*)d_in[8];
  const float* Rk     = (const float*)d_in[9];
  const float* cell_b = (const float*)d_in[10];
  const float* gn_w   = (const float*)d_in[11];
  const float* ln2_w  = (const float*)d_in[12];
  const float* ff_w1  = (const float*)d_in[13];
  const float* ff_b1  = (const float*)d_in[14];
  const float* ff_w2  = (const float*)d_in[15];
  const float* ff_b2  = (const float*)d_in[16];
  const float* postw  = (const float*)d_in[17];
  const float* cw1    = (const float*)d_in[18];
  const float* cb1    = (const float*)d_in[19];
  const float* cw2    = (const float*)d_in[20];
  const float* cb2    = (const float*)d_in[21];
  float* out = (float*)d_out;

  char* ws = (char*)d_ws;
  size_t off = 0;
  float* x      = (float*)(ws + off); off += (size_t)BT*128*4;
  u16*   xn_bf  = (u16*)(ws + off);   off += (size_t)BT*128*2;
  u16*   xc_bf  = (u16*)(ws + off);   off += (size_t)BT*128*2;
  u16*   gates  = (u16*)(ws + off);
  u16*   act    = gates;              off += (size_t)BT*512*2;   // act aliases gates
  u16*   w1T    = (u16*)(ws + off);   off += (size_t)NBB*384*128*2;
  u16*   w2T    = (u16*)(ws + off);   off += (size_t)NBB*128*192*2;
  u16*   gifT   = (u16*)(ws + off);   off += (size_t)NBB*HH*64*32*2;
  u16*   gzoT   = (u16*)(ws + off);   off += (size_t)NBB*HH*64*32*2;

  k_convert<<<704, 256, 0, stream>>>(ff_w1, ff_w2, Wi, Wf, Wz, Wo, w1T, w2T, gifT, gzoT);
  k_embed<<<(BT*32 + 255)/256, 256, 0, stream>>>(tok, emb, x);
  for (int nb = 0; nb < NBB; nb++){
    k_lnconv<<<BB*4, 256, 0, stream>>>(x, ln1_w, conv_w, conv_b, xn_bf, xc_bf, nb);
    k_gates<<<dim3(BT/64, HH, 2), 256, 0, stream>>>(xc_bf, xn_bf, gifT, gzoT, gates, nb);
    k_scan<<<512, 256, 0, stream>>>(gates, Rk, cell_b, gn_w, x, nb);
    k_ff1<<<BT/64, 256, 0, stream>>>(x, ln2_w, w1T, ff_b1, act, nb);
    k_ff2<<<BT/64, 256, 0, stream>>>(act, w2T, ff_b2, x, nb);
  }
  k_pool_cls<<<BB, 256, 0, stream>>>(x, postw, cw1, cb1, cw2, cb2, out);
}

// Round 6
// 438.453 us; speedup vs baseline: 1.3075x; 1.0933x over previous
//
#include <hip/hip_runtime.h>

typedef unsigned short u16;
typedef unsigned int u32;
typedef __attribute__((ext_vector_type(8))) short short8;
typedef __attribute__((ext_vector_type(4))) short s16x4;
typedef __attribute__((ext_vector_type(4))) float f32x4;
typedef __attribute__((ext_vector_type(2))) float f32x2;
typedef __attribute__((ext_vector_type(2))) int i32x2;

#define BB 512
#define TT 128
#define DD 128
#define HH 4
#define NBB 2
#define BT (BB*TT)
#define EPSF 1e-5f
#define LOG2E 1.4426950408889634f

__device__ __forceinline__ float bf2f(u16 u){ return __uint_as_float(((u32)u) << 16); }
__device__ __forceinline__ u16 f2bf(float f){
  u32 x = __float_as_uint(f);
  u32 r = x + 0x7fffu + ((x >> 16) & 1u);
  return (u16)(r >> 16);
}
__device__ __forceinline__ float bcastf(float v, int lane){
  return __uint_as_float(__builtin_amdgcn_readlane(__float_as_uint(v), lane));
}
__device__ __forceinline__ float fast_tanh(float x){
  float ax = fabsf(x);
  float e = __expf(-2.f * ax);
  float t = (1.f - e) / (1.f + e);
  return copysignf(t, x);
}
__device__ __forceinline__ float gelu_tanh(float x){
  float u = 0.7978845608028654f * (x + 0.044715f * x * x * x);
  return 0.5f * x * (1.f + fast_tanh(u));
}
// DPP add helper: v += dpp_move(v); masked/OOB lanes add 0 (old=0 either mode).
#define DPP_ADD(v, ctrl, rmask, bc) \
  v += __int_as_float(__builtin_amdgcn_update_dpp(0, __float_as_int(v), (ctrl), (rmask), 0xf, (bc)))
// full-wave (64-lane) sum via DPP, broadcast to all lanes through SGPR
__device__ __forceinline__ float wsum64(float v){
  DPP_ADD(v, 0x111, 0xf, true);   // row_shr:1
  DPP_ADD(v, 0x112, 0xf, true);   // row_shr:2
  DPP_ADD(v, 0x114, 0xf, true);   // row_shr:4
  DPP_ADD(v, 0x118, 0xf, true);   // row_shr:8  -> lanes 15/31/47/63 = row sums
  DPP_ADD(v, 0x142, 0xa, false);  // row_bcast:15 -> lane31=r0+r1, lane63=r2+r3
  DPP_ADD(v, 0x143, 0xc, false);  // row_bcast:31 -> lane63 = total
  return bcastf(v, 63);
}
// sum over lanes 0..31; total lands in lane 31
__device__ __forceinline__ float rsum_rows01(float v){
  DPP_ADD(v, 0x111, 0xf, true);
  DPP_ADD(v, 0x112, 0xf, true);
  DPP_ADD(v, 0x114, 0xf, true);
  DPP_ADD(v, 0x118, 0xf, true);
  DPP_ADD(v, 0x142, 0xa, false);  // lane31 = total(0..31)
  return v;
}
// lanes<32 receive v from lane+32 (VALU permlane32_swap; no LDS).
__device__ __forceinline__ float down32(float v){
  i32x2 r = __builtin_amdgcn_permlane32_swap(__float_as_int(v), __float_as_int(v), false, false);
  return __int_as_float(r.y);
}

// ---------------- weight conversion to bf16 (transposed for MFMA B-frags) ----
__global__ __launch_bounds__(256) void k_convert(
    const float* __restrict__ ff_w1, const float* __restrict__ ff_w2,
    const float* __restrict__ Wi, const float* __restrict__ Wf,
    const float* __restrict__ Wz, const float* __restrict__ Wo,
    u16* __restrict__ w1T, u16* __restrict__ w2T,
    u16* __restrict__ gifT, u16* __restrict__ gzoT){
  int tid = blockIdx.x * 256 + threadIdx.x;
  const int n1 = NBB*384*128;
  if (tid < n1){
    int nb = tid / (384*128); int r = tid - nb*384*128; int n = r >> 7, k = r & 127;
    w1T[tid] = f2bf(ff_w1[(nb*128 + k)*384 + n]); return;
  }
  tid -= n1;
  const int n2 = NBB*128*192;
  if (tid < n2){
    int nb = tid / (128*192); int r = tid - nb*128*192; int n = r / 192, k = r - n*192;
    w2T[tid] = f2bf(ff_w2[(nb*192 + k)*128 + n]); return;
  }
  tid -= n2;
  const int n3 = NBB*HH*64*32;
  if (tid < n3){
    int nb = tid / (HH*64*32); int r = tid - nb*HH*64*32;
    int h = r >> 11; int r2 = r & 2047; int n = r2 >> 5, k = r2 & 31;
    const float* W = (n < 32) ? Wi : Wf; int nn = n & 31;
    gifT[tid] = f2bf(W[((nb*HH + h)*32 + k)*32 + nn]); return;
  }
  tid -= n3;
  if (tid < n3){
    int nb = tid / (HH*64*32); int r = tid - nb*HH*64*32;
    int h = r >> 11; int r2 = r & 2047; int n = r2 >> 5, k = r2 & 31;
    const float* W = (n < 32) ? Wz : Wo; int nn = n & 31;
    gzoT[tid] = f2bf(W[((nb*HH + h)*32 + k)*32 + nn]); return;
  }
}

// ---------------- embedding gather ----------------
__global__ __launch_bounds__(256) void k_embed(const int* __restrict__ tok,
                                               const float* __restrict__ emb,
                                               float* __restrict__ x){
  int tid = blockIdx.x * 256 + threadIdx.x;
  int row = tid >> 5, c = tid & 31;
  if (row < BT){
    ((f32x4*)x)[(size_t)row*32 + c] = ((const f32x4*)emb)[(size_t)tok[row]*32 + c];
  }
}

// ---------------- LN1 + causal depthwise conv + silu ----------------
__global__ __launch_bounds__(256) void k_lnconv(const float* __restrict__ x,
    const float* __restrict__ ln1_w, const float* __restrict__ conv_w,
    const float* __restrict__ conv_b, u16* __restrict__ xn_bf,
    u16* __restrict__ xc_bf, int nb){
  __shared__ float lnbuf[35][128];
  int b = blockIdx.x >> 2, tile = blockIdx.x & 3;
  int t0 = tile * 32;
  int wid = threadIdx.x >> 6, l = threadIdx.x & 63;
  for (int tt = wid; tt < 35; tt += 4){
    int t = t0 - 3 + tt;
    if (t < 0){
      lnbuf[tt][2*l] = 0.f; lnbuf[tt][2*l+1] = 0.f;
    } else {
      float2 v = ((const float2*)(x + (size_t)(b*TT + t)*128))[l];
      float s  = wsum64(v.x + v.y);
      float sq = wsum64(v.x*v.x + v.y*v.y);
      float mu = s * (1.f/128.f);
      float var = sq * (1.f/128.f) - mu*mu;
      float rs = rsqrtf(var + EPSF);
      float2 w = ((const float2*)(ln1_w + nb*128))[l];
      float y0 = (v.x - mu)*rs*w.x, y1 = (v.y - mu)*rs*w.y;
      lnbuf[tt][2*l] = y0; lnbuf[tt][2*l+1] = y1;
      if (tt >= 3){
        u32 pk = (u32)f2bf(y0) | ((u32)f2bf(y1) << 16);
        ((u32*)(xn_bf + (size_t)(b*TT + t)*128))[l] = pk;
      }
    }
  }
  __syncthreads();
  for (int e = threadIdx.x; e < 32*128; e += 256){
    int tt = e >> 7, d = e & 127;
    float s = conv_b[nb*128 + d];
    #pragma unroll
    for (int k = 0; k < 4; k++)
      s += lnbuf[tt + k][d] * conv_w[(nb*128 + d)*4 + k];
    float sig = 1.f / (1.f + __expf(-s));
    xc_bf[(size_t)(b*TT + t0 + tt)*128 + d] = f2bf(s * sig);
  }
}

// ---------------- gate projections (MFMA) ----------------
// grid BT/64; wave wid = head h; handles z=0,1 and 4 row-groups (32 MFMA/wave)
// gates layout: [b][h][t>>3][col(128)][t&7]
__global__ __launch_bounds__(256) void k_gates(const u16* __restrict__ xc_bf,
    const u16* __restrict__ xn_bf, const u16* __restrict__ gifT,
    const u16* __restrict__ gzoT, u16* __restrict__ gates, int nb){
  int m0 = blockIdx.x * 64;
  int b = m0 >> 7;
  int t00 = m0 & 127;
  int h = threadIdx.x >> 6, l = threadIdx.x & 63;
  short8 bfr[2][4];
  {
    const u16* B0 = gifT + (size_t)(nb*HH + h)*64*32;
    const u16* B1 = gzoT + (size_t)(nb*HH + h)*64*32;
    #pragma unroll
    for (int jt = 0; jt < 4; jt++){
      bfr[0][jt] = *(const short8*)(B0 + (jt*16 + (l & 15))*32 + (l >> 4)*8);
      bfr[1][jt] = *(const short8*)(B1 + (jt*16 + (l & 15))*32 + (l >> 4)*8);
    }
  }
  u16* gb = gates + (size_t)(b*HH + h)*TT*128;
  #pragma unroll
  for (int z = 0; z < 2; z++){
    const u16* A = z ? xn_bf : xc_bf;
    #pragma unroll
    for (int rg = 0; rg < 4; rg++){
      int r0 = m0 + rg*16;
      short8 a = *(const short8*)(A + (size_t)(r0 + (l & 15))*128 + h*32 + (l >> 4)*8);
      int tt = t00 + rg*16 + (l >> 4)*4;          // 4-aligned
      #pragma unroll
      for (int jt = 0; jt < 4; jt++){
        f32x4 acc = {0.f, 0.f, 0.f, 0.f};
        acc = __builtin_amdgcn_mfma_f32_16x16x32_bf16(a, bfr[z][jt], acc, 0, 0, 0);
        int cloc = z*64 + jt*16 + (l & 15);
        s16x4 pk;
        #pragma unroll
        for (int r = 0; r < 4; r++) pk[r] = (short)f2bf(acc[r]);
        *(s16x4*)(gb + ((size_t)(tt >> 3)*128 + cloc)*8 + (tt & 7)) = pk;
      }
    }
  }
}

// ---------------- sLSTM recurrent scan + group-norm + residual ----------------
// one wave per (batch, head); lane l owns gate cols l and l+64.
// lanes<32: (ir, zr); lanes>=32: (fr, og). No LDS/DS ops, no divergence in loop.
__global__ __launch_bounds__(256, 2) void k_scan(const u16* __restrict__ gates,
    const float* __restrict__ Rk, const float* __restrict__ cell_b,
    const float* __restrict__ gn_w, float* __restrict__ x,
    float* __restrict__ dump, int nb){
  int wid = threadIdx.x >> 6, l = threadIdx.x & 63;
  int pair = blockIdx.x * 4 + wid;       // 2048 chains
  int b = pair >> 2, h = pair & 3;
  f32x2 rk[32];
  const float* Rkh = Rk + (size_t)(nb*HH + h)*32*128;
  #pragma unroll
  for (int d = 0; d < 32; d++){
    rk[d].x = Rkh[d*128 + l];
    rk[d].y = Rkh[d*128 + l + 64];
  }
  f32x2 cb = { cell_b[(nb*HH + h)*128 + l], cell_b[(nb*HH + h)*128 + l + 64] };
  int e = l & 31;
  bool lo = (l < 32);
  float gnw = gn_w[nb*128 + h*32 + e];
  float hs = 0.f, cs = 0.f, ns = 0.f, ms = 0.f;
  const u16* gbase = gates + (size_t)(b*HH + h)*TT*128;
  // always-exec residual pointers: hi lanes use a per-wave dump row (stride 0)
  float* xp = lo ? (x + (size_t)(b*TT)*128 + h*32 + e) : (dump + pair*32 + e);
  int xstr = lo ? 128 : 0;
  float xnext = xp[0];
  short8 ga = *(const short8*)(gbase + (size_t)l*8);
  short8 gb = *(const short8*)(gbase + (size_t)(l + 64)*8);
  for (int t8 = 0; t8 < 16; t8++){
    // prefetch next 8 steps (1KB-coalesced per wave; overreads at end — ws mapped)
    short8 na  = *(const short8*)(gbase + ((size_t)(t8+1)*128 + l)*8);
    short8 nb2 = *(const short8*)(gbase + ((size_t)(t8+1)*128 + l + 64)*8);
    #pragma unroll
    for (int k = 0; k < 8; k++){
      float xcur = xnext;
      xnext = xp[xstr];                  // next row (hi lanes: same dump addr)
      f32x2 acc0 = { bf2f((u16)ga[k]) + cb.x, bf2f((u16)gb[k]) + cb.y };
      f32x2 acc1 = {0.f, 0.f}, acc2 = {0.f, 0.f}, acc3 = {0.f, 0.f};
      #pragma unroll
      for (int d = 0; d < 32; d += 4){
        float h0 = bcastf(hs, d),   h1 = bcastf(hs, d+1);
        float h2 = bcastf(hs, d+2), h3 = bcastf(hs, d+3);
        acc0 = __builtin_elementwise_fma((f32x2){h0,h0}, rk[d],   acc0);
        acc1 = __builtin_elementwise_fma((f32x2){h1,h1}, rk[d+1], acc1);
        acc2 = __builtin_elementwise_fma((f32x2){h2,h2}, rk[d+2], acc2);
        acc3 = __builtin_elementwise_fma((f32x2){h3,h3}, rk[d+3], acc3);
      }
      f32x2 rr = (acc0 + acc1) + (acc2 + acc3);
      float r0 = rr.x, r1 = rr.y;          // lanes<32: ir, zr ; lanes>=32: fr, og
      float fx = down32(r0);               // lanes<32 get fr[e]
      float ox = down32(r1);               // lanes<32 get og[e]
      // gating — valid in lanes<32; upper lanes compute garbage (dump-only)
      float mnew = fmaxf(fx + ms, r0);
      float ig = __builtin_amdgcn_exp2f((r0 - mnew) * LOG2E);
      float fg = __builtin_amdgcn_exp2f((fx + ms - mnew) * LOG2E);
      float e2 = __builtin_amdgcn_exp2f(2.f * LOG2E * r1);
      float th = fmaf(-2.f, __builtin_amdgcn_rcpf(e2 + 1.f), 1.f);   // tanh(zr)
      cs = fmaf(fg, cs, ig * th);
      ns = fmaf(fg, ns, ig);
      ms = mnew;
      // hs = cs * sigmoid(og) / ns  with one rcp
      float se = __builtin_amdgcn_exp2f(-ox * LOG2E);
      hs = cs * __builtin_amdgcn_rcpf(fmaf(ns, se, ns));
      // group norm over lanes 0..31 via DPP (no LDS)
      float s = rsum_rows01(hs);
      float sq = rsum_rows01(hs * hs);
      float mu = bcastf(s, 31) * (1.f/32.f);
      float var = bcastf(sq, 31) * (1.f/32.f) - mu*mu;
      float yn = (hs - mu) * __builtin_amdgcn_rsqf(var + EPSF) * gnw;
      xp[0] = xcur + yn;
      xp += xstr;
    }
    ga = na; gb = nb2;
  }
}

// ---------------- LN2 + FFN up-proj + gelu*up (MFMA) ----------------
__global__ __launch_bounds__(256) void k_ff1(const float* __restrict__ x,
    const float* __restrict__ ln2_w, const u16* __restrict__ w1T,
    const float* __restrict__ ff_b1, u16* __restrict__ act, int nb){
  __shared__ u16 lnb[64][128];
  int m0 = blockIdx.x * 64;
  int wid = threadIdx.x >> 6, l = threadIdx.x & 63;
  float2 w = ((const float2*)(ln2_w + nb*128))[l];
  for (int rr = 0; rr < 16; rr++){
    int row = wid*16 + rr;
    float2 v = ((const float2*)(x + (size_t)(m0 + row)*128))[l];
    float s  = wsum64(v.x + v.y);
    float sq = wsum64(v.x*v.x + v.y*v.y);
    float mu = s * (1.f/128.f);
    float var = sq * (1.f/128.f) - mu*mu;
    float rs = rsqrtf(var + EPSF);
    float y0 = (v.x - mu)*rs*w.x, y1 = (v.y - mu)*rs*w.y;
    ((u32*)lnb[row])[l] = (u32)f2bf(y0) | ((u32)f2bf(y1) << 16);
  }
  __syncthreads();
  short8 a[4];
  #pragma unroll
  for (int c = 0; c < 4; c++)
    a[c] = *(const short8*)(&lnb[wid*16 + (l & 15)][c*32 + (l >> 4)*8]);
  const u16* W = w1T + (size_t)nb*384*128;
  f32x4 acc[24];
  #pragma unroll
  for (int jt = 0; jt < 24; jt++){
    acc[jt] = {0.f, 0.f, 0.f, 0.f};
    #pragma unroll
    for (int c = 0; c < 4; c++){
      short8 bf = *(const short8*)(W + (size_t)(jt*16 + (l & 15))*128 + c*32 + (l >> 4)*8);
      acc[jt] = __builtin_amdgcn_mfma_f32_16x16x32_bf16(a[c], bf, acc[jt], 0, 0, 0);
    }
  }
  #pragma unroll
  for (int jt = 0; jt < 12; jt++){
    int colg = jt*16 + (l & 15);
    float bg = ff_b1[nb*384 + colg];
    float bu = ff_b1[nb*384 + 192 + colg];
    #pragma unroll
    for (int r = 0; r < 4; r++){
      int row = m0 + wid*16 + (l >> 4)*4 + r;
      float gh = acc[jt][r] + bg;
      float uh = acc[jt + 12][r] + bu;
      act[(size_t)row*192 + colg] = f2bf(gelu_tanh(gh) * uh);
    }
  }
}

// ---------------- FFN down-proj + residual (MFMA) ----------------
__global__ __launch_bounds__(256) void k_ff2(const u16* __restrict__ act,
    const u16* __restrict__ w2T, const float* __restrict__ ff_b2,
    float* __restrict__ x, int nb){
  int m0 = blockIdx.x * 64;
  int wid = threadIdx.x >> 6, l = threadIdx.x & 63;
  short8 a[6];
  #pragma unroll
  for (int c = 0; c < 6; c++)
    a[c] = *(const short8*)(act + (size_t)(m0 + wid*16 + (l & 15))*192 + c*32 + (l >> 4)*8);
  const u16* W = w2T + (size_t)nb*128*192;
  #pragma unroll
  for (int jt = 0; jt < 8; jt++){
    f32x4 acc = {0.f, 0.f, 0.f, 0.f};
    #pragma unroll
    for (int c = 0; c < 6; c++){
      short8 bf = *(const short8*)(W + (size_t)(jt*16 + (l & 15))*192 + c*32 + (l >> 4)*8);
      acc = __builtin_amdgcn_mfma_f32_16x16x32_bf16(a[c], bf, acc, 0, 0, 0);
    }
    int col = jt*16 + (l & 15);
    float bias = ff_b2[nb*128 + col];
    #pragma unroll
    for (int r = 0; r < 4; r++){
      int row = m0 + wid*16 + (l >> 4)*4 + r;
      x[(size_t)row*128 + col] += acc[r] + bias;
    }
  }
}

// ---------------- post-LN + mean-pool + classifier ----------------
__global__ __launch_bounds__(256) void k_pool_cls(const float* __restrict__ x,
    const float* __restrict__ pw, const float* __restrict__ w1,
    const float* __restrict__ b1, const float* __restrict__ w2,
    const float* __restrict__ b2, float* __restrict__ out){
  __shared__ float red[4][128];
  __shared__ float pooled[128];
  __shared__ float h1s[64];
  int b = blockIdx.x;
  int wid = threadIdx.x >> 6, l = threadIdx.x & 63;
  float2 w = ((const float2*)pw)[l];
  float ax = 0.f, ay = 0.f;
  for (int t = wid; t < TT; t += 4){
    float2 v = ((const float2*)(x + (size_t)(b*TT + t)*128))[l];
    float s  = wsum64(v.x + v.y);
    float sq = wsum64(v.x*v.x + v.y*v.y);
    float mu = s * (1.f/128.f);
    float var = sq * (1.f/128.f) - mu*mu;
    float rs = rsqrtf(var + EPSF);
    ax += (v.x - mu)*rs*w.x;
    ay += (v.y - mu)*rs*w.y;
  }
  red[wid][2*l] = ax; red[wid][2*l+1] = ay;
  __syncthreads();
  if (threadIdx.x < 128){
    int d = threadIdx.x;
    pooled[d] = (red[0][d] + red[1][d] + red[2][d] + red[3][d]) * (1.f/128.f);
  }
  __syncthreads();
  if (threadIdx.x < 64){
    int j = threadIdx.x;
    float s = b1[j];
    for (int d = 0; d < 128; d++) s += pooled[d] * w1[d*64 + j];
    h1s[j] = fmaxf(s, 0.f);
  }
  __syncthreads();
  if (threadIdx.x < 2){
    int j = threadIdx.x;
    float s = b2[j];
    for (int k = 0; k < 64; k++) s += h1s[k] * w2[k*2 + j];
    out[b*2 + j] = s;
  }
}

extern "C" void kernel_launch(void* const* d_in, const int* in_sizes, int n_in,
                              void* d_out, int out_size, void* d_ws, size_t ws_size,
                              hipStream_t stream){
  const int*   tok    = (const int*)d_in[0];
  const float* emb    = (const float*)d_in[1];
  const float* ln1_w  = (const float*)d_in[2];
  const float* conv_w = (const float*)d_in[3];
  const float* conv_b = (const float*)d_in[4];
  const float* Wi     = (const float*)d_in[5];
  const float* Wf     = (const float*)d_in[6];
  const float* Wz     = (const float*)d_in[7];
  const float* Wo     = (const float*)d_in[8];
  const float* Rk     = (const float*)d_in[9];
  const float* cell_b = (const float*)d_in[10];
  const float* gn_w   = (const float*)d_in[11];
  const float* ln2_w  = (const float*)d_in[12];
  const float* ff_w1  = (const float*)d_in[13];
  const float* ff_b1  = (const float*)d_in[14];
  const float* ff_w2  = (const float*)d_in[15];
  const float* ff_b2  = (const float*)d_in[16];
  const float* postw  = (const float*)d_in[17];
  const float* cw1    = (const float*)d_in[18];
  const float* cb1    = (const float*)d_in[19];
  const float* cw2    = (const float*)d_in[20];
  const float* cb2    = (const float*)d_in[21];
  float* out = (float*)d_out;

  char* ws = (char*)d_ws;
  size_t off = 0;
  float* x      = (float*)(ws + off); off += (size_t)BT*128*4;
  u16*   xn_bf  = (u16*)(ws + off);   off += (size_t)BT*128*2;
  u16*   xc_bf  = (u16*)(ws + off);   off += (size_t)BT*128*2;
  u16*   gates  = (u16*)(ws + off);
  u16*   act    = gates;              off += (size_t)BT*512*2;   // act aliases gates
  u16*   w1T    = (u16*)(ws + off);   off += (size_t)NBB*384*128*2;
  u16*   w2T    = (u16*)(ws + off);   off += (size_t)NBB*128*192*2;
  u16*   gifT   = (u16*)(ws + off);   off += (size_t)NBB*HH*64*32*2;
  u16*   gzoT   = (u16*)(ws + off);   off += (size_t)NBB*HH*64*32*2;
  float* dump   = (float*)xn_bf;      // dead during k_scan; 256KB used

  k_convert<<<704, 256, 0, stream>>>(ff_w1, ff_w2, Wi, Wf, Wz, Wo, w1T, w2T, gifT, gzoT);
  k_embed<<<(BT*32 + 255)/256, 256, 0, stream>>>(tok, emb, x);
  for (int nb = 0; nb < NBB; nb++){
    k_lnconv<<<BB*4, 256, 0, stream>>>(x, ln1_w, conv_w, conv_b, xn_bf, xc_bf, nb);
    k_gates<<<BT/64, 256, 0, stream>>>(xc_bf, xn_bf, gifT, gzoT, gates, nb);
    k_scan<<<512, 256, 0, stream>>>(gates, Rk, cell_b, gn_w, x, dump, nb);
    k_ff1<<<BT/64, 256, 0, stream>>>(x, ln2_w, w1T, ff_b1, act, nb);
    k_ff2<<<BT/64, 256, 0, stream>>>(act, w2T, ff_b2, x, nb);
  }
  k_pool_cls<<<BB, 256, 0, stream>>>(x, postw, cw1, cb1, cw2, cb2, out);
}